// Round 3
// baseline (36628.528 us; speedup 1.0000x reference)
//
#include <hip/hip_runtime.h>
#include <hip/hip_bf16.h>
#include <stdint.h>

#define T_STEPS 8192
#define HID     1024
#define IN_F    2048
#define N3H     3072   // 3*HID

// ---------------------------------------------------------------------------
// Exchange format: one u32 word per h element; low 2 mantissa bits = step tag
// (step & 3). Double-buffered (buffer s&1 holds h for step s); stale content
// is from step s-2 whose tag differs mod 4. Polled/stored as u64 pairs.
// h_0 = 0.0f, tag 0 -> all-zero init.
// ---------------------------------------------------------------------------
__global__ void init_pairs(unsigned int* pairs) {
    int i = blockIdx.x * blockDim.x + threadIdx.x;
    if (i < 2 * HID) pairs[i] = 0u;
}

// ---------------------------------------------------------------------------
// Phase 1: gi[t, j'] = x[t] . w_ih[j'] + b_ih[j']  (unchanged from round 2)
// ---------------------------------------------------------------------------
#define GBM 64
#define GBN 64
#define GBK 32

__global__ __launch_bounds__(256) void gi_gemm(
    const float* __restrict__ feat,   // [8192][2048]
    const float* __restrict__ rew,    // [8192]
    const float* __restrict__ w_ih,   // [3072][2049]
    const float* __restrict__ b_ih,   // [3072]
    float* __restrict__ gi)           // [8192][3072]
{
    __shared__ float As[GBK][GBM + 4];
    __shared__ float Bs[GBK][GBN + 4];

    const int tid = threadIdx.x;
    const int n0 = blockIdx.x * GBN;
    const int t0 = blockIdx.y * GBM;
    const int tx = tid & 15, ty = tid >> 4;
    const int lr = tid >> 3;
    const int lc = (tid & 7) * 4;

    float acc[4][4] = {{0.f}};

    for (int k0 = 0; k0 < IN_F; k0 += GBK) {
#pragma unroll
        for (int hh = 0; hh < 2; hh++) {
            const int r = lr + 32 * hh;
            const float4 a = *(const float4*)(feat + (size_t)(t0 + r) * IN_F + k0 + lc);
            As[lc + 0][r] = a.x; As[lc + 1][r] = a.y;
            As[lc + 2][r] = a.z; As[lc + 3][r] = a.w;
            const float* brow = w_ih + (size_t)(n0 + r) * (IN_F + 1) + k0 + lc;
            Bs[lc + 0][r] = brow[0]; Bs[lc + 1][r] = brow[1];
            Bs[lc + 2][r] = brow[2]; Bs[lc + 3][r] = brow[3];
        }
        __syncthreads();
#pragma unroll
        for (int kk = 0; kk < GBK; kk++) {
            const float4 a = *(const float4*)&As[kk][ty * 4];
            const float4 b = *(const float4*)&Bs[kk][tx * 4];
            acc[0][0] += a.x * b.x; acc[0][1] += a.x * b.y; acc[0][2] += a.x * b.z; acc[0][3] += a.x * b.w;
            acc[1][0] += a.y * b.x; acc[1][1] += a.y * b.y; acc[1][2] += a.y * b.z; acc[1][3] += a.y * b.w;
            acc[2][0] += a.z * b.x; acc[2][1] += a.z * b.y; acc[2][2] += a.z * b.z; acc[2][3] += a.z * b.w;
            acc[3][0] += a.w * b.x; acc[3][1] += a.w * b.y; acc[3][2] += a.w * b.z; acc[3][3] += a.w * b.w;
        }
        __syncthreads();
    }

    const int m = t0 + ty * 4;
    const int n = n0 + tx * 4;
    float wlast[4], bi[4];
#pragma unroll
    for (int c = 0; c < 4; c++) {
        wlast[c] = w_ih[(size_t)(n + c) * (IN_F + 1) + IN_F];
        bi[c]    = b_ih[n + c];
    }
#pragma unroll
    for (int r = 0; r < 4; r++) {
        const float rwv = rew[m + r];
        float4 v;
        v.x = acc[r][0] + rwv * wlast[0] + bi[0];
        v.y = acc[r][1] + rwv * wlast[1] + bi[1];
        v.z = acc[r][2] + rwv * wlast[2] + bi[2];
        v.w = acc[r][3] + rwv * wlast[3] + bi[3];
        *(float4*)(gi + (size_t)(m + r) * N3H + n) = v;
    }
}

// ---------------------------------------------------------------------------
// DPP wave-64 sum: result lands in lane 63 (VALU pipe only, no LDS).
// ---------------------------------------------------------------------------
__device__ __forceinline__ float wave_red_sum(float x) {
    int v;
    v = __builtin_amdgcn_update_dpp(0, __float_as_int(x), 0x111, 0xf, 0xf, true); // row_shr:1
    x += __int_as_float(v);
    v = __builtin_amdgcn_update_dpp(0, __float_as_int(x), 0x112, 0xf, 0xf, true); // row_shr:2
    x += __int_as_float(v);
    v = __builtin_amdgcn_update_dpp(0, __float_as_int(x), 0x114, 0xf, 0xf, true); // row_shr:4
    x += __int_as_float(v);
    v = __builtin_amdgcn_update_dpp(0, __float_as_int(x), 0x118, 0xf, 0xf, true); // row_shr:8
    x += __int_as_float(v);
    v = __builtin_amdgcn_update_dpp(0, __float_as_int(x), 0x142, 0xf, 0xf, true); // row_bcast:15
    x += __int_as_float(v);
    v = __builtin_amdgcn_update_dpp(0, __float_as_int(x), 0x143, 0xf, 0xf, true); // row_bcast:31
    x += __int_as_float(v);
    return x;   // lane 63 = full sum
}

__device__ __forceinline__ float bcast_lane(float x, int lane) {
    return __int_as_float(__builtin_amdgcn_readlane(__float_as_int(x), lane));
}

__device__ __forceinline__ float fsig(float x) {
    return __builtin_amdgcn_rcpf(1.f + __expf(-x));
}
__device__ __forceinline__ float ftanh(float x) {
    return 2.f * __builtin_amdgcn_rcpf(1.f + __expf(-2.f * x)) - 1.f;
}

// ---------------------------------------------------------------------------
// Phase 2: barrier-free GRU scan. 64 wgs x 256 threads = 256 waves; wave g
// owns j = 4g..4g+3 with all 12 recurrent weight rows in REGISTERS
// (48 float4/lane). Each wave polls the full tagged h vector straight into
// its dot-fragment registers (8 u64 loads), computes, DPP-reduces, and
// stores 16 B. No __syncthreads in the loop: the tag protocol is the only
// synchronization; fused tag+data + double buffer bounds global skew to
// 2 steps (tag mod 4 disambiguates).
// ---------------------------------------------------------------------------
__global__ __launch_bounds__(256, 1) void gru_scan(
    const float* __restrict__ gi,     // [8192][3072]
    const float* __restrict__ w_hh,   // [3072][1024]
    const float* __restrict__ b_hh,   // [3072]
    unsigned int* pairs,              // [2][1024] tagged fp32
    float* __restrict__ out)          // [1024]
{
    const int tid  = threadIdx.x;
    const int lane = tid & 63;
    const int gw   = blockIdx.x * 4 + (tid >> 6);   // global wave id 0..255
    const int j0   = gw * 4;                        // this wave's 4 outputs

    // recurrent weights -> registers: wf[jl][gate][m4] = w_hh[gate*H+j0+jl][4*(lane+64*m4)..+3]
    float4 wf[4][3][4];
#pragma unroll
    for (int jl = 0; jl < 4; jl++)
#pragma unroll
        for (int g = 0; g < 3; g++)
#pragma unroll
            for (int m4 = 0; m4 < 4; m4++)
                wf[jl][g][m4] = *(const float4*)(
                    w_hh + (size_t)(g * HID + j0 + jl) * HID + 4 * (lane + 64 * m4));

    float bh[4][3];
#pragma unroll
    for (int jl = 0; jl < 4; jl++)
#pragma unroll
        for (int g = 0; g < 3; g++)
            bh[jl][g] = b_hh[g * HID + j0 + jl];

    unsigned long long* const p64 = (unsigned long long*)pairs;  // [2][512]
    const int srcl = gw & 63;       // lane holding h4[j0/4]
    const int m4s  = gw >> 6;       // fragment index holding h4[j0/4]

    for (int i = 0; i < T_STEPS; i++) {
        const int t = T_STEPS - 1 - i;
        unsigned long long* buf  = p64 + (size_t)(i & 1) * (HID / 2);
        unsigned long long* nbuf = p64 + (size_t)((i + 1) & 1) * (HID / 2);

        // gi prefetch (wave-uniform addresses; issued before the poll)
        const float* girow = gi + (size_t)t * N3H;
        float gg[4][3];
#pragma unroll
        for (int jl = 0; jl < 4; jl++)
#pragma unroll
            for (int g = 0; g < 3; g++)
                gg[jl][g] = girow[g * HID + j0 + jl];

        // poll the whole h (tagged) straight into fragment registers
        const unsigned long long want64 =
            (unsigned long long)(unsigned)(i & 3) * 0x0000000100000001ull;
        const unsigned long long tagm = 0x0000000300000003ull;
        unsigned long long v[8];
        for (;;) {
            bool ok = true;
#pragma unroll
            for (int m4 = 0; m4 < 4; m4++) {
                const int q = 2 * (lane + 64 * m4);
                v[2 * m4]     = __hip_atomic_load(buf + q,     __ATOMIC_RELAXED, __HIP_MEMORY_SCOPE_AGENT);
                v[2 * m4 + 1] = __hip_atomic_load(buf + q + 1, __ATOMIC_RELAXED, __HIP_MEMORY_SCOPE_AGENT);
            }
#pragma unroll
            for (int k = 0; k < 8; k++) ok &= ((v[k] & tagm) == want64);
            if (ok) break;
        }
        float4 h4[4];
#pragma unroll
        for (int m4 = 0; m4 < 4; m4++) {
            h4[m4].x = __uint_as_float((unsigned)(v[2 * m4] & 0xffffffffu));
            h4[m4].y = __uint_as_float((unsigned)(v[2 * m4] >> 32));
            h4[m4].z = __uint_as_float((unsigned)(v[2 * m4 + 1] & 0xffffffffu));
            h4[m4].w = __uint_as_float((unsigned)(v[2 * m4 + 1] >> 32));
        }

        // 12 dot-partials (192 FMA/lane), then DPP reduce -> lane63 -> broadcast
        float acc[4][3] = {};
#pragma unroll
        for (int m4 = 0; m4 < 4; m4++) {
            const float4 hv = h4[m4];
#pragma unroll
            for (int jl = 0; jl < 4; jl++)
#pragma unroll
                for (int g = 0; g < 3; g++) {
                    const float4 w = wf[jl][g][m4];
                    acc[jl][g] += hv.x * w.x + hv.y * w.y + hv.z * w.z + hv.w * w.w;
                }
        }
        float s[4][3];
#pragma unroll
        for (int jl = 0; jl < 4; jl++)
#pragma unroll
            for (int g = 0; g < 3; g++)
                s[jl][g] = bcast_lane(wave_red_sum(acc[jl][g]), 63);

        // previous h for my 4 j's: fragment m4s at lane srcl (wave-uniform)
        float hold[4];
        {
            const float4 hsrc = (m4s == 0) ? h4[0] : (m4s == 1) ? h4[1] : (m4s == 2) ? h4[2] : h4[3];
            hold[0] = bcast_lane(hsrc.x, srcl);
            hold[1] = bcast_lane(hsrc.y, srcl);
            hold[2] = bcast_lane(hsrc.z, srcl);
            hold[3] = bcast_lane(hsrc.w, srcl);
        }

        float hnew[4];
#pragma unroll
        for (int jl = 0; jl < 4; jl++) {
            const float r = fsig(gg[jl][0] + s[jl][0] + bh[jl][0]);
            const float z = fsig(gg[jl][1] + s[jl][1] + bh[jl][1]);
            const float n = ftanh(gg[jl][2] + r * (s[jl][2] + bh[jl][2]));
            hnew[jl] = (1.f - z) * n + z * hold[jl];
        }

        if (i == T_STEPS - 1) {
            if (lane == 0) {
                out[j0 + 0] = hnew[0]; out[j0 + 1] = hnew[1];
                out[j0 + 2] = hnew[2]; out[j0 + 3] = hnew[3];
            }
        } else if (lane == 0) {
            const unsigned tag = (unsigned)((i + 1) & 3);
            const unsigned u0 = (__float_as_uint(hnew[0]) & ~3u) | tag;
            const unsigned u1 = (__float_as_uint(hnew[1]) & ~3u) | tag;
            const unsigned u2 = (__float_as_uint(hnew[2]) & ~3u) | tag;
            const unsigned u3 = (__float_as_uint(hnew[3]) & ~3u) | tag;
            const unsigned long long pk01 = ((unsigned long long)u1 << 32) | u0;
            const unsigned long long pk23 = ((unsigned long long)u3 << 32) | u2;
            __hip_atomic_store(nbuf + (j0 >> 1),     pk01, __ATOMIC_RELAXED, __HIP_MEMORY_SCOPE_AGENT);
            __hip_atomic_store(nbuf + (j0 >> 1) + 1, pk23, __ATOMIC_RELAXED, __HIP_MEMORY_SCOPE_AGENT);
        }
    }
}

// ---------------------------------------------------------------------------
extern "C" void kernel_launch(void* const* d_in, const int* in_sizes, int n_in,
                              void* d_out, int out_size, void* d_ws, size_t ws_size,
                              hipStream_t stream) {
    const float* feat = (const float*)d_in[0];  // [8192,2048]
    const float* rew  = (const float*)d_in[1];  // [8192]
    const float* w_ih = (const float*)d_in[2];  // [3072,2049]
    const float* w_hh = (const float*)d_in[3];  // [3072,1024]
    const float* b_ih = (const float*)d_in[4];  // [3072]
    const float* b_hh = (const float*)d_in[5];  // [3072]
    float* out = (float*)d_out;                 // [1024]

    float* gi = (float*)d_ws;                                   // 96 MB
    unsigned int* pairs =
        (unsigned int*)((char*)d_ws + (size_t)T_STEPS * N3H * sizeof(float));

    hipLaunchKernelGGL(init_pairs, dim3(8), dim3(256), 0, stream, pairs);
    hipLaunchKernelGGL(gi_gemm, dim3(N3H / GBN, T_STEPS / GBM), dim3(256), 0, stream,
                       feat, rew, w_ih, b_ih, gi);
    hipLaunchKernelGGL(gru_scan, dim3(64), dim3(256), 0, stream,
                       gi, w_hh, b_hh, pairs, out);
}

// Round 4
// 18471.040 us; speedup vs baseline: 1.9830x; 1.9830x over previous
//
#include <hip/hip_runtime.h>
#include <hip/hip_bf16.h>
#include <stdint.h>

#define T_STEPS 8192
#define HID     1024
#define IN_F    2048
#define N3H     3072   // 3*HID
#define NREP    8      // exchange-buffer replicas (spread coherence-point lines)

// ---------------------------------------------------------------------------
// Exchange format: one u32 per h element; low 2 mantissa bits = step tag
// (step & 3). Double-buffered (buffer s&1 holds h of step s); stale content
// is from step s-2 (tag differs mod 4). Replicated NREP x: producers store
// to every replica, consumer wg g polls replica g&(NREP-1) only. Fused
// tag+data keeps the 2-buffer race-freedom proof: a wave's step-i data reads
// ARE its step-i detect, and its step-(i+1) store certifies it finished
// reading step i, independent of replica.
// h_0 = 0.0f with tag 0 == 0x0 -> zero-init.
// ---------------------------------------------------------------------------
__global__ void init_pairs(unsigned int* pairs) {
    int i = blockIdx.x * blockDim.x + threadIdx.x;
    if (i < 2 * NREP * HID) pairs[i] = 0u;
}

// scoped 16B load: bypass L1/L2 (sc0 sc1) so cross-XCD stores are visible;
// per-32-bit-word atomicity is guaranteed by natural alignment (tearing
// across words is fine -- each word carries its own tag).
__device__ __forceinline__ uint4 load_x4_scoped(const unsigned int* p) {
    uint4 r;
    asm volatile("global_load_dwordx4 %0, %1, off sc0 sc1\n\t"
                 "s_waitcnt vmcnt(0)"
                 : "=v"(r) : "v"(p) : "memory");
    return r;
}
__device__ __forceinline__ void store_scoped(unsigned int* p, unsigned int v) {
    asm volatile("global_store_dword %0, %1, off sc0 sc1"
                 :: "v"(p), "v"(v) : "memory");
}

// ---------------------------------------------------------------------------
// Phase 1: gi[t, j'] = x[t] . w_ih[j'] + b_ih[j']  (unchanged, ~1.4 ms)
// ---------------------------------------------------------------------------
#define GBM 64
#define GBN 64
#define GBK 32

__global__ __launch_bounds__(256) void gi_gemm(
    const float* __restrict__ feat,   // [8192][2048]
    const float* __restrict__ rew,    // [8192]
    const float* __restrict__ w_ih,   // [3072][2049]
    const float* __restrict__ b_ih,   // [3072]
    float* __restrict__ gi)           // [8192][3072]
{
    __shared__ float As[GBK][GBM + 4];
    __shared__ float Bs[GBK][GBN + 4];

    const int tid = threadIdx.x;
    const int n0 = blockIdx.x * GBN;
    const int t0 = blockIdx.y * GBM;
    const int tx = tid & 15, ty = tid >> 4;
    const int lr = tid >> 3;
    const int lc = (tid & 7) * 4;

    float acc[4][4] = {{0.f}};

    for (int k0 = 0; k0 < IN_F; k0 += GBK) {
#pragma unroll
        for (int hh = 0; hh < 2; hh++) {
            const int r = lr + 32 * hh;
            const float4 a = *(const float4*)(feat + (size_t)(t0 + r) * IN_F + k0 + lc);
            As[lc + 0][r] = a.x; As[lc + 1][r] = a.y;
            As[lc + 2][r] = a.z; As[lc + 3][r] = a.w;
            const float* brow = w_ih + (size_t)(n0 + r) * (IN_F + 1) + k0 + lc;
            Bs[lc + 0][r] = brow[0]; Bs[lc + 1][r] = brow[1];
            Bs[lc + 2][r] = brow[2]; Bs[lc + 3][r] = brow[3];
        }
        __syncthreads();
#pragma unroll
        for (int kk = 0; kk < GBK; kk++) {
            const float4 a = *(const float4*)&As[kk][ty * 4];
            const float4 b = *(const float4*)&Bs[kk][tx * 4];
            acc[0][0] += a.x * b.x; acc[0][1] += a.x * b.y; acc[0][2] += a.x * b.z; acc[0][3] += a.x * b.w;
            acc[1][0] += a.y * b.x; acc[1][1] += a.y * b.y; acc[1][2] += a.y * b.z; acc[1][3] += a.y * b.w;
            acc[2][0] += a.z * b.x; acc[2][1] += a.z * b.y; acc[2][2] += a.z * b.z; acc[2][3] += a.z * b.w;
            acc[3][0] += a.w * b.x; acc[3][1] += a.w * b.y; acc[3][2] += a.w * b.z; acc[3][3] += a.w * b.w;
        }
        __syncthreads();
    }

    const int m = t0 + ty * 4;
    const int n = n0 + tx * 4;
    float wlast[4], bi[4];
#pragma unroll
    for (int c = 0; c < 4; c++) {
        wlast[c] = w_ih[(size_t)(n + c) * (IN_F + 1) + IN_F];
        bi[c]    = b_ih[n + c];
    }
#pragma unroll
    for (int r = 0; r < 4; r++) {
        const float rwv = rew[m + r];
        float4 v;
        v.x = acc[r][0] + rwv * wlast[0] + bi[0];
        v.y = acc[r][1] + rwv * wlast[1] + bi[1];
        v.z = acc[r][2] + rwv * wlast[2] + bi[2];
        v.w = acc[r][3] + rwv * wlast[3] + bi[3];
        *(float4*)(gi + (size_t)(m + r) * N3H + n) = v;
    }
}

// ---------------------------------------------------------------------------
// Phase 2: persistent GRU scan. 256 wgs x 256 threads; wg g owns j in
// [4g,4g+4), one j per wave. Weights in static LDS (48 KB -- no
// PromoteAlloca demotion risk). Poll: one scoped dwordx4 per thread from
// replica g&7 (256 transactions/wg-sweep, 8x line spreading).
// ---------------------------------------------------------------------------
__global__ __launch_bounds__(256, 2) void gru_scan(
    const float* __restrict__ gi,     // [8192][3072]
    const float* __restrict__ w_hh,   // [3072][1024]
    const float* __restrict__ b_hh,   // [3072]
    unsigned int* pairs,              // [2][NREP][1024] tagged fp32
    float* __restrict__ out)          // [1024]
{
    __shared__ float4 w_lds[3][4][HID / 4];  // 48 KB
    __shared__ float4 h_lds[HID / 4];        // 4 KB

    const int tid  = threadIdx.x;
    const int g    = blockIdx.x;      // 0..255
    const int j0   = g * 4;
    const int wave = tid >> 6;
    const int lane = tid & 63;
    const int myj  = j0 + wave;
    const int rep  = g & (NREP - 1);

#pragma unroll
    for (int r = 0; r < 12; r++) {
        const int gate = r >> 2, jl = r & 3;
        const float4* src = (const float4*)(w_hh + (size_t)(gate * HID + j0 + jl) * HID);
        w_lds[gate][jl][tid] = src[tid];
    }
    float b_r = 0.f, b_z = 0.f, b_n = 0.f;
    if (lane == 0) {
        b_r = b_hh[myj];
        b_z = b_hh[HID + myj];
        b_n = b_hh[2 * HID + myj];
    }
    __syncthreads();

    float* h_f = (float*)h_lds;

    for (int i = 0; i < T_STEPS; i++) {
        const int t = T_STEPS - 1 - i;
        unsigned int* rbuf  = pairs + ((size_t)(i & 1) * NREP + rep) * HID;
        unsigned int* sbase = pairs + (size_t)((i + 1) & 1) * NREP * HID + myj;

        // gi prefetch (issued before the spin; lane0 only uses results)
        float gi_r = 0.f, gi_z = 0.f, gi_n = 0.f;
        if (lane == 0) {
            const float* girow = gi + (size_t)t * N3H;
            gi_r = girow[myj];
            gi_z = girow[HID + myj];
            gi_n = girow[2 * HID + myj];
        }

        // poll: one dwordx4 per thread until all 4 words carry tag (i&3)
        {
            const unsigned int want = (unsigned int)(i & 3);
            uint4 v;
            for (;;) {
                v = load_x4_scoped(rbuf + tid * 4);
                if (((v.x & 3u) == want) && ((v.y & 3u) == want) &&
                    ((v.z & 3u) == want) && ((v.w & 3u) == want))
                    break;
                __builtin_amdgcn_s_sleep(1);
            }
            float4 hv;
            hv.x = __uint_as_float(v.x);
            hv.y = __uint_as_float(v.y);
            hv.z = __uint_as_float(v.z);
            hv.w = __uint_as_float(v.w);
            h_lds[tid] = hv;
        }
        __syncthreads();

        // wave `wave` computes the 3 recurrent dots for j = myj
        float ar = 0.f, az = 0.f, an = 0.f;
        const float4* wr = w_lds[0][wave];
        const float4* wz = w_lds[1][wave];
        const float4* wn = w_lds[2][wave];
#pragma unroll
        for (int m4 = 0; m4 < 4; m4++) {
            const int idx = lane + 64 * m4;
            const float4 h4 = h_lds[idx];
            const float4 r4 = wr[idx];
            const float4 z4 = wz[idx];
            const float4 n4 = wn[idx];
            ar += h4.x * r4.x + h4.y * r4.y + h4.z * r4.z + h4.w * r4.w;
            az += h4.x * z4.x + h4.y * z4.y + h4.z * z4.z + h4.w * z4.w;
            an += h4.x * n4.x + h4.y * n4.y + h4.z * n4.z + h4.w * n4.w;
        }
#pragma unroll
        for (int off = 32; off > 0; off >>= 1) {
            ar += __shfl_down(ar, off);
            az += __shfl_down(az, off);
            an += __shfl_down(an, off);
        }

        if (lane == 0) {
            const float hjold = h_f[myj];
            const float r = 1.f / (1.f + __expf(-(gi_r + ar + b_r)));
            const float z = 1.f / (1.f + __expf(-(gi_z + az + b_z)));
            const float n = tanhf(gi_n + r * (an + b_n));
            const float hnew = (1.f - z) * n + z * hjold;
            if (i == T_STEPS - 1) {
                out[myj] = hnew;
            } else {
                const unsigned int pk =
                    (__float_as_uint(hnew) & ~3u) | (unsigned int)((i + 1) & 3);
#pragma unroll
                for (int rr = 0; rr < NREP; rr++)
                    store_scoped(sbase + rr * HID, pk);
            }
        }
        __syncthreads();   // protect h_lds before next iteration's poll fill
    }
}

// ---------------------------------------------------------------------------
extern "C" void kernel_launch(void* const* d_in, const int* in_sizes, int n_in,
                              void* d_out, int out_size, void* d_ws, size_t ws_size,
                              hipStream_t stream) {
    const float* feat = (const float*)d_in[0];  // [8192,2048]
    const float* rew  = (const float*)d_in[1];  // [8192]
    const float* w_ih = (const float*)d_in[2];  // [3072,2049]
    const float* w_hh = (const float*)d_in[3];  // [3072,1024]
    const float* b_ih = (const float*)d_in[4];  // [3072]
    const float* b_hh = (const float*)d_in[5];  // [3072]
    float* out = (float*)d_out;                 // [1024]

    float* gi = (float*)d_ws;                                   // 96 MB
    unsigned int* pairs =
        (unsigned int*)((char*)d_ws + (size_t)T_STEPS * N3H * sizeof(float));  // 64 KB

    hipLaunchKernelGGL(init_pairs, dim3((2 * NREP * HID + 255) / 256), dim3(256), 0, stream, pairs);
    hipLaunchKernelGGL(gi_gemm, dim3(N3H / GBN, T_STEPS / GBM), dim3(256), 0, stream,
                       feat, rew, w_ih, b_ih, gi);
    hipLaunchKernelGGL(gru_scan, dim3(256), dim3(256), 0, stream,
                       gi, w_hh, b_hh, pairs, out);
}